// Round 4
// baseline (1899.965 us; speedup 1.0000x reference)
//
#include <hip/hip_runtime.h>

typedef unsigned short ushort_t;
typedef unsigned int uint_t;

#define N_NODES 65536
#define N_EDGES 262144

typedef __attribute__((ext_vector_type(8))) short bf16x8;
typedef __attribute__((ext_vector_type(4))) float f32x4;

// ---------- bf16 helpers ----------
__device__ __forceinline__ ushort_t f2b(float x) {
  uint_t u = __float_as_uint(x);
  u += 0x7fffu + ((u >> 16) & 1u);  // RNE
  return (ushort_t)(u >> 16);
}
__device__ __forceinline__ void dec8(uint4 v, float* f) {
  f[0] = __uint_as_float(v.x << 16); f[1] = __uint_as_float(v.x & 0xffff0000u);
  f[2] = __uint_as_float(v.y << 16); f[3] = __uint_as_float(v.y & 0xffff0000u);
  f[4] = __uint_as_float(v.z << 16); f[5] = __uint_as_float(v.z & 0xffff0000u);
  f[6] = __uint_as_float(v.w << 16); f[7] = __uint_as_float(v.w & 0xffff0000u);
}
__device__ __forceinline__ uint4 enc8(const float* f) {
  uint4 v;
  v.x = (uint_t)f2b(f[0]) | ((uint_t)f2b(f[1]) << 16);
  v.y = (uint_t)f2b(f[2]) | ((uint_t)f2b(f[3]) << 16);
  v.z = (uint_t)f2b(f[4]) | ((uint_t)f2b(f[5]) << 16);
  v.w = (uint_t)f2b(f[6]) | ((uint_t)f2b(f[7]) << 16);
  return v;
}
__device__ __forceinline__ void ld8(const float* p, float* f) {
  float4 v0 = *(const float4*)p;
  float4 v1 = *(const float4*)(p + 4);
  f[0]=v0.x; f[1]=v0.y; f[2]=v0.z; f[3]=v0.w;
  f[4]=v1.x; f[5]=v1.y; f[6]=v1.z; f[7]=v1.w;
}

#define ELUF(v) ((v) > 0.f ? (v) : __expf(v) - 1.f)

// async global->LDS, 16B per lane; lds base must be wave-uniform (lane deposits at base+lane*16)
__device__ __forceinline__ void async16(void* lds, const void* g) {
  __builtin_amdgcn_global_load_lds(
      (const __attribute__((address_space(1))) void*)g,
      (__attribute__((address_space(3))) void*)lds, 16, 0, 0);
}

// ---------- weight transpose+cvt: dst[m][n*K+k] = bf16(src[m][k*N+n]) ----------
__global__ void wt_kernel(const float* __restrict__ src, ushort_t* __restrict__ dst,
                          int K, int N) {
  long m = blockIdx.y;
  long base = m * (long)K * N;
  int tid = blockIdx.x * 256 + threadIdx.x;
  if (tid >= K * N) return;
  int k = tid % K, n = tid / K;
  dst[base + (long)n * K + k] = f2b(src[base + (long)k * N + n]);
}

// ---------- folded score vectors: gbuf[mp][v][c] = bf16( sum_d Wep[mp][c][d] * vec_v[d] )
// v = 0..3 -> a_e(L0) head v ; v = 4..7 -> a_edge(L0) head v-4.  c in [0,64).
__global__ void g_kernel(const float* __restrict__ Wep, const float* __restrict__ a_e,
                         const float* __restrict__ a_edge, ushort_t* __restrict__ gbuf) {
  int mp = blockIdx.x;
  int t = threadIdx.x;       // 512 threads
  int v = t >> 6, c = t & 63;
  const float* vec = (v < 4 ? a_e + mp * 2048 + v * 256
                            : a_edge + mp * 2048 + (v - 4) * 256);
  const float* wrow = Wep + (long)mp * 64 * 256 + (long)c * 256;
  float s = 0.f;
#pragma unroll
  for (int d = 0; d < 256; d += 4) {
    float4 wv = *(const float4*)(wrow + d);
    float4 av = *(const float4*)(vec + d);
    s += wv.x * av.x + wv.y * av.y + wv.z * av.z + wv.w * av.w;
  }
  gbuf[mp * 512 + v * 64 + c] = f2b(s);
}

// ---------- dual MFMA GEMM: out{0,1}[rows][256] = bf16( A_f32[rows][256] @ Wt{0,1}^T ) ----------
__global__ __launch_bounds__(256, 2) void gemm_mfma2(
    const float* __restrict__ A, const ushort_t* __restrict__ Wt0,
    const ushort_t* __restrict__ Wt1, ushort_t* __restrict__ out0,
    ushort_t* __restrict__ out1) {
  __shared__ __align__(16) char smem[4096 + 16384 + 16384];
  ushort_t (*sA)[32]  = (ushort_t(*)[32])smem;             // [64][32]
  ushort_t (*sB0)[32] = (ushort_t(*)[32])(smem + 4096);    // [256][32]
  ushort_t (*sB1)[32] = (ushort_t(*)[32])(smem + 20480);   // [256][32]
  int t = threadIdx.x, w = t >> 6, l = t & 63;
  long r0 = (long)blockIdx.x * 64;
  f32x4 zero = {0.f, 0.f, 0.f, 0.f};
  f32x4 acc0[4][4], acc1[4][4];
#pragma unroll
  for (int mt = 0; mt < 4; ++mt)
#pragma unroll
    for (int nt = 0; nt < 4; ++nt) { acc0[mt][nt] = zero; acc1[mt][nt] = zero; }

  for (int kc = 0; kc < 8; ++kc) {
    __syncthreads();
    {  // stage A (f32 -> bf16)
      int r = t >> 2, ks8 = (t & 3) * 8;
      float f[8]; ld8(A + (r0 + r) * 256 + kc * 32 + ks8, f);
      *(uint4*)&sA[r][ks8] = enc8(f);
    }
#pragma unroll
    for (int j = 0; j < 4; ++j) {
      int u = (w * 4 + j) * 64 + l;
      int n = u >> 2, ks = u & 3;
      async16((char*)sB0 + (w * 4 + j) * 1024, Wt0 + (long)n * 256 + kc * 32 + ks * 8);
      async16((char*)sB1 + (w * 4 + j) * 1024, Wt1 + (long)n * 256 + kc * 32 + ks * 8);
    }
    __syncthreads();
    bf16x8 af[4];
#pragma unroll
    for (int mt = 0; mt < 4; ++mt)
      af[mt] = *(const bf16x8*)&sA[mt * 16 + (l & 15)][(l >> 4) * 8];
#pragma unroll
    for (int nt = 0; nt < 4; ++nt) {
      bf16x8 b0 = *(const bf16x8*)&sB0[w * 64 + nt * 16 + (l & 15)][(l >> 4) * 8];
      bf16x8 b1 = *(const bf16x8*)&sB1[w * 64 + nt * 16 + (l & 15)][(l >> 4) * 8];
#pragma unroll
      for (int mt = 0; mt < 4; ++mt) {
        acc0[mt][nt] = __builtin_amdgcn_mfma_f32_16x16x32_bf16(af[mt], b0, acc0[mt][nt], 0, 0, 0);
        acc1[mt][nt] = __builtin_amdgcn_mfma_f32_16x16x32_bf16(af[mt], b1, acc1[mt][nt], 0, 0, 0);
      }
    }
  }
#pragma unroll
  for (int mt = 0; mt < 4; ++mt)
#pragma unroll
    for (int nt = 0; nt < 4; ++nt)
#pragma unroll
      for (int i = 0; i < 4; ++i) {
        long row = r0 + mt * 16 + (l >> 4) * 4 + i;
        int col = w * 64 + nt * 16 + (l & 15);
        out0[row * 256 + col] = f2b(acc0[mt][nt][i]);
        out1[row * 256 + col] = f2b(acc1[mt][nt][i]);
      }
}

// ---------- eproj GEMM: outb[rows][256] = bf16(A @ Wt^T), + fused scores[rows][4] = A . a_vec^T
__global__ __launch_bounds__(256, 2) void gemm_eproj(
    const ushort_t* __restrict__ A, const ushort_t* __restrict__ Wt,
    const float* __restrict__ a_vec,  // f32 [4][256]
    ushort_t* __restrict__ outb, float* __restrict__ sco) {
  __shared__ __align__(16) char smem[4096 + 16384 + 8192];
  ushort_t (*sA)[32]   = (ushort_t(*)[32])smem;            // [64][32]
  ushort_t (*sB)[32]   = (ushort_t(*)[32])(smem + 4096);   // [256][32]
  ushort_t (*sAe)[256] = (ushort_t(*)[256])(smem + 20480); // [16][256], rows 4..15 zero
  int t = threadIdx.x, w = t >> 6, l = t & 63;
  long r0 = (long)blockIdx.x * 64;

  {  // stage a_vec^T as B-layout tile (16 cols, cols>=4 zero)
    int row = t >> 4, seg = (t & 15) * 16;
    float f[16];
    if (row < 4) {
      ld8(a_vec + row * 256 + seg, f);
      ld8(a_vec + row * 256 + seg + 8, f + 8);
    } else {
#pragma unroll
      for (int i = 0; i < 16; ++i) f[i] = 0.f;
    }
    *(uint4*)&sAe[row][seg] = enc8(f);
    *(uint4*)&sAe[row][seg + 8] = enc8(f + 8);
  }

  f32x4 zero = {0.f, 0.f, 0.f, 0.f};
  f32x4 acc[4][4];
  f32x4 accs[4];
#pragma unroll
  for (int mt = 0; mt < 4; ++mt) {
    accs[mt] = zero;
#pragma unroll
    for (int nt = 0; nt < 4; ++nt) acc[mt][nt] = zero;
  }

  for (int kc = 0; kc < 8; ++kc) {
    __syncthreads();
    async16((char*)sA + w * 1024, A + (r0 + (t >> 2)) * 256 + kc * 32 + (t & 3) * 8);
#pragma unroll
    for (int j = 0; j < 4; ++j) {  // stage B
      int u = (w * 4 + j) * 64 + l;
      int n = u >> 2, ks = u & 3;
      async16((char*)sB + (w * 4 + j) * 1024, Wt + (long)n * 256 + kc * 32 + ks * 8);
    }
    __syncthreads();
    bf16x8 af[4], bf[4];
#pragma unroll
    for (int mt = 0; mt < 4; ++mt)
      af[mt] = *(const bf16x8*)&sA[mt * 16 + (l & 15)][(l >> 4) * 8];
#pragma unroll
    for (int nt = 0; nt < 4; ++nt)
      bf[nt] = *(const bf16x8*)&sB[w * 64 + nt * 16 + (l & 15)][(l >> 4) * 8];
#pragma unroll
    for (int mt = 0; mt < 4; ++mt)
#pragma unroll
      for (int nt = 0; nt < 4; ++nt)
        acc[mt][nt] = __builtin_amdgcn_mfma_f32_16x16x32_bf16(af[mt], bf[nt], acc[mt][nt], 0, 0, 0);
    if (w == 0) {  // fused scores: A @ a_vec^T
      bf16x8 bs = *(const bf16x8*)&sAe[l & 15][kc * 32 + (l >> 4) * 8];
#pragma unroll
      for (int mt = 0; mt < 4; ++mt)
        accs[mt] = __builtin_amdgcn_mfma_f32_16x16x32_bf16(af[mt], bs, accs[mt], 0, 0, 0);
    }
  }
#pragma unroll
  for (int mt = 0; mt < 4; ++mt)
#pragma unroll
    for (int nt = 0; nt < 4; ++nt)
#pragma unroll
      for (int i = 0; i < 4; ++i) {
        long row = r0 + mt * 16 + (l >> 4) * 4 + i;
        int col = w * 64 + nt * 16 + (l & 15);
        outb[row * 256 + col] = f2b(acc[mt][nt][i]);
      }
  if (w == 0 && (l & 15) < 4) {
#pragma unroll
    for (int mt = 0; mt < 4; ++mt)
#pragma unroll
      for (int i = 0; i < 4; ++i) {
        long row = r0 + mt * 16 + (l >> 4) * 4 + i;
        sco[row * 4 + (l & 15)] = accs[mt][i];
      }
  }
}

// ---------- edge mega-kernel v2: 3 blocks/CU, fixed swizzle ----------
// Phase1: tile = eemb @ W_eprep -> LDS swizzled; fused sea/sed0 vs folded 64-dim g-vectors.
// PassA: tile @ W_nb(L0) -> eproj0.  PassB: tile @ W_e(L0) -> overwrite tile (= eprojE).
// Phase3: per-kc in-place combine elu(eprojE + a0*xprojE[n0] + a1*xprojE[n1]) @ W_nb(L1)
//         -> eprojL1 + fused sed1.
// Swizzle: 16B-block index cb = (col>>3) ^ (row&7)  (2-way max on all access patterns).
__global__ __launch_bounds__(256, 3) void edge_mega(
    const float* __restrict__ eemb,       // [E][64] f32 (this mp)
    const ushort_t* __restrict__ WtEp,    // [256][64]
    const ushort_t* __restrict__ WtN0,    // [256][256] W_nb L0
    const ushort_t* __restrict__ WtE0,    // [256][256] W_e  L0
    const ushort_t* __restrict__ WtN1,    // [256][256] W_nb L1
    const ushort_t* __restrict__ gbuf,    // [8][64] folded score vecs (this mp)
    const float* __restrict__ a_ed1,      // [4][256] a_edge L1
    const int* __restrict__ ena,          // [E][2]
    const ushort_t* __restrict__ xprojE,  // [N][256] base @ W_e(L0)
    const float* __restrict__ xan,        // [N][4]   base . a_n(L0)
    ushort_t* __restrict__ eproj0, float* __restrict__ sed0,
    ushort_t* __restrict__ eprojL1, float* __restrict__ sed1) {
  __shared__ __align__(16) char smem[54272];
  char* sEc            = smem;                              // [64 rows][512B] bf16 swizzled
  ushort_t (*sB)[32]   = (ushort_t(*)[32])(smem + 32768);   // [256][32]
  ushort_t (*sSc0)[64] = (ushort_t(*)[64])(smem + 49152);   // [8][64] phase-1 score B
  ushort_t (*sT)[32]   = (ushort_t(*)[32])(smem + 50176);   // [64][32] phase-1 A-stage
  float* sSea          = (float*)(smem + 50176);            // [64][4]  (after phase 1)
  ushort_t (*sEd1)[256]= (ushort_t(*)[256])(smem + 51200);  // [4][256] (after phase 1)
  int t = threadIdx.x, w = t >> 6, l = t & 63;
  long e0 = (long)blockIdx.x * 64;
  bf16x8 z8 = {0, 0, 0, 0, 0, 0, 0, 0};

  // per-thread edge endpoints (phase 3); issue early
  int r3 = t >> 2, cq = t & 3;
  int n0r = ena[(e0 + r3) * 2 + 0];
  int n1r = ena[(e0 + r3) * 2 + 1];
  float4 x0s = *(const float4*)(xan + (long)n0r * 4);
  float4 x1s = *(const float4*)(xan + (long)n1r * 4);

  if (t < 64)  // stage folded score tile [8][64]
    *(uint4*)&sSc0[t >> 3][(t & 7) * 8] = *(const uint4*)(gbuf + (t >> 3) * 64 + (t & 7) * 8);

  f32x4 zero = {0.f, 0.f, 0.f, 0.f};
  f32x4 acc[4][4];
  f32x4 accs[4];
#pragma unroll
  for (int mt = 0; mt < 4; ++mt) {
    accs[mt] = zero;
#pragma unroll
    for (int nt = 0; nt < 4; ++nt) acc[mt][nt] = zero;
  }

  // ---- phase 1: tile = eemb @ WtEp^T (K=64) + fused L0 scores ----
  for (int kc = 0; kc < 2; ++kc) {
    __syncthreads();
    {  // stage A chunk (f32 -> bf16)
      int r = t >> 2, ks8 = (t & 3) * 8;
      float f[8]; ld8(eemb + (e0 + r) * 64 + kc * 32 + ks8, f);
      *(uint4*)&sT[r][ks8] = enc8(f);
    }
#pragma unroll
    for (int j = 0; j < 4; ++j) {
      int u = (w * 4 + j) * 64 + l;
      int n = u >> 2, ks = u & 3;
      async16((char*)sB + (w * 4 + j) * 1024, WtEp + (long)n * 64 + kc * 32 + ks * 8);
    }
    __syncthreads();
    bf16x8 af[4], bf[4];
#pragma unroll
    for (int mt = 0; mt < 4; ++mt)
      af[mt] = *(const bf16x8*)&sT[mt * 16 + (l & 15)][(l >> 4) * 8];
#pragma unroll
    for (int nt = 0; nt < 4; ++nt)
      bf[nt] = *(const bf16x8*)&sB[w * 64 + nt * 16 + (l & 15)][(l >> 4) * 8];
#pragma unroll
    for (int mt = 0; mt < 4; ++mt)
#pragma unroll
      for (int nt = 0; nt < 4; ++nt)
        acc[mt][nt] = __builtin_amdgcn_mfma_f32_16x16x32_bf16(af[mt], bf[nt], acc[mt][nt], 0, 0, 0);
    if (w == 0) {  // fused sea (cols 0-3) / sed0 (cols 4-7)
      bf16x8 bs = ((l & 15) < 8)
          ? *(const bf16x8*)&sSc0[l & 15][kc * 32 + (l >> 4) * 8] : z8;
#pragma unroll
      for (int mt = 0; mt < 4; ++mt)
        accs[mt] = __builtin_amdgcn_mfma_f32_16x16x32_bf16(af[mt], bs, accs[mt], 0, 0, 0);
    }
  }
  // write tile to sEc (bf16, swizzled)
#pragma unroll
  for (int mt = 0; mt < 4; ++mt)
#pragma unroll
    for (int nt = 0; nt < 4; ++nt)
#pragma unroll
      for (int i = 0; i < 4; ++i) {
        int row = mt * 16 + (l >> 4) * 4 + i;
        int col = w * 64 + nt * 16 + (l & 15);
        int cb = (col >> 3) ^ (row & 7);
        *(ushort_t*)(sEc + row * 512 + cb * 16 + (col & 7) * 2) = f2b(acc[mt][nt][i]);
      }
  __syncthreads();  // publish sEc; sT now dead

  if (w == 0) {  // score epilogue: sea -> sSea (LDS), sed0 -> global
    int c = l & 15;
    if (c < 8) {
#pragma unroll
      for (int mt = 0; mt < 4; ++mt)
#pragma unroll
        for (int i = 0; i < 4; ++i) {
          int row = mt * 16 + (l >> 4) * 4 + i;
          float v = accs[mt][i];
          if (c < 4) sSea[row * 4 + c] = v;
          else sed0[(e0 + row) * 4 + (c - 4)] = v;
        }
    }
  }
  if (t < 128) {  // stage a_edge(L1) as bf16 [4][256]
    int row = t >> 5, dof = (t & 31) * 8;
    float f[8]; ld8(a_ed1 + row * 256 + dof, f);
    *(uint4*)&sEd1[row][dof] = enc8(f);
  }

  // ---- pass A: eproj0 = tile @ W_nb(L0) ----
#pragma unroll
  for (int mt = 0; mt < 4; ++mt)
#pragma unroll
    for (int nt = 0; nt < 4; ++nt) acc[mt][nt] = zero;
  for (int kc = 0; kc < 8; ++kc) {
    __syncthreads();
#pragma unroll
    for (int j = 0; j < 4; ++j) {
      int u = (w * 4 + j) * 64 + l;
      int n = u >> 2, ks = u & 3;
      async16((char*)sB + (w * 4 + j) * 1024, WtN0 + (long)n * 256 + kc * 32 + ks * 8);
    }
    __syncthreads();
    bf16x8 af[4], bf[4];
#pragma unroll
    for (int mt = 0; mt < 4; ++mt) {
      int row = mt * 16 + (l & 15);
      int cb = (kc * 4 + (l >> 4)) ^ (row & 7);
      af[mt] = *(const bf16x8*)(sEc + row * 512 + cb * 16);
    }
#pragma unroll
    for (int nt = 0; nt < 4; ++nt)
      bf[nt] = *(const bf16x8*)&sB[w * 64 + nt * 16 + (l & 15)][(l >> 4) * 8];
#pragma unroll
    for (int mt = 0; mt < 4; ++mt)
#pragma unroll
      for (int nt = 0; nt < 4; ++nt)
        acc[mt][nt] = __builtin_amdgcn_mfma_f32_16x16x32_bf16(af[mt], bf[nt], acc[mt][nt], 0, 0, 0);
  }
#pragma unroll
  for (int mt = 0; mt < 4; ++mt)
#pragma unroll
    for (int nt = 0; nt < 4; ++nt)
#pragma unroll
      for (int i = 0; i < 4; ++i) {
        long row = e0 + mt * 16 + (l >> 4) * 4 + i;
        int col = w * 64 + nt * 16 + (l & 15);
        eproj0[row * 256 + col] = f2b(acc[mt][nt][i]);
      }

  // ---- pass B: eprojE = tile @ W_e(L0) -> overwrite sEc after full K-loop ----
#pragma unroll
  for (int mt = 0; mt < 4; ++mt)
#pragma unroll
    for (int nt = 0; nt < 4; ++nt) acc[mt][nt] = zero;
  for (int kc = 0; kc < 8; ++kc) {
    __syncthreads();
#pragma unroll
    for (int j = 0; j < 4; ++j) {
      int u = (w * 4 + j) * 64 + l;
      int n = u >> 2, ks = u & 3;
      async16((char*)sB + (w * 4 + j) * 1024, WtE0 + (long)n * 256 + kc * 32 + ks * 8);
    }
    __syncthreads();
    bf16x8 af[4], bf[4];
#pragma unroll
    for (int mt = 0; mt < 4; ++mt) {
      int row = mt * 16 + (l & 15);
      int cb = (kc * 4 + (l >> 4)) ^ (row & 7);
      af[mt] = *(const bf16x8*)(sEc + row * 512 + cb * 16);
    }
#pragma unroll
    for (int nt = 0; nt < 4; ++nt)
      bf[nt] = *(const bf16x8*)&sB[w * 64 + nt * 16 + (l & 15)][(l >> 4) * 8];
#pragma unroll
    for (int mt = 0; mt < 4; ++mt)
#pragma unroll
      for (int nt = 0; nt < 4; ++nt)
        acc[mt][nt] = __builtin_amdgcn_mfma_f32_16x16x32_bf16(af[mt], bf[nt], acc[mt][nt], 0, 0, 0);
  }
  __syncthreads();  // all reads of old tile complete
#pragma unroll
  for (int mt = 0; mt < 4; ++mt)
#pragma unroll
    for (int nt = 0; nt < 4; ++nt)
#pragma unroll
      for (int i = 0; i < 4; ++i) {
        int row = mt * 16 + (l >> 4) * 4 + i;
        int col = w * 64 + nt * 16 + (l & 15);
        int cb = (col >> 3) ^ (row & 7);
        *(ushort_t*)(sEc + row * 512 + cb * 16 + (col & 7) * 2) = f2b(acc[mt][nt][i]);
      }

  // per-thread 2-way softmax (row r3) from sSea + xan
  float a0h[4], a1h[4];
  {
    float xs0[4] = {x0s.x, x0s.y, x0s.z, x0s.w};
    float xs1[4] = {x1s.x, x1s.y, x1s.z, x1s.w};
#pragma unroll
    for (int h = 0; h < 4; ++h) {
      float sE = sSea[r3 * 4 + h];
      float s0 = xs0[h] + sE; s0 = s0 > 0.f ? s0 : 0.2f * s0;
      float s1 = xs1[h] + sE; s1 = s1 > 0.f ? s1 : 0.2f * s1;
      float mx = fmaxf(s0, s1);
      float g0 = __expf(s0 - mx), g1 = __expf(s1 - mx);
      float inv = 1.f / (g0 + g1);
      a0h[h] = g0 * inv; a1h[h] = g1 * inv;
    }
  }

  // ---- phase 3: in-place combine + @ W_nb(L1), fused sed1 ----
  f32x4 accP[4][4];
#pragma unroll
  for (int mt = 0; mt < 4; ++mt) {
    accs[mt] = zero;
#pragma unroll
    for (int nt = 0; nt < 4; ++nt) accP[mt][nt] = zero;
  }
  const ushort_t* p0 = xprojE + (long)n0r * 256 + cq * 8;
  const ushort_t* p1 = xprojE + (long)n1r * 256 + cq * 8;
  for (int kc = 0; kc < 8; ++kc) {
    __syncthreads();  // publishes sEc overwrite (kc=0); guards sB restage
#pragma unroll
    for (int j = 0; j < 4; ++j) {
      int u = (w * 4 + j) * 64 + l;
      int n = u >> 2, ks = u & 3;
      async16((char*)sB + (w * 4 + j) * 1024, WtN1 + (long)n * 256 + kc * 32 + ks * 8);
    }
    {  // in-place combine of this k-chunk (head h = kc>>1); thread owns its 16B
      int h = kc >> 1;
      int cb = (kc * 4 + cq) ^ (r3 & 7);
      float ep[8], x0[8], x1[8], y[8];
      dec8(*(const uint4*)(sEc + r3 * 512 + cb * 16), ep);
      dec8(*(const uint4*)(p0 + kc * 32), x0);
      dec8(*(const uint4*)(p1 + kc * 32), x1);
#pragma unroll
      for (int d = 0; d < 8; ++d) {
        float v = ep[d] + a0h[h] * x0[d] + a1h[h] * x1[d];
        y[d] = ELUF(v);
      }
      *(uint4*)(sEc + r3 * 512 + cb * 16) = enc8(y);
    }
    __syncthreads();
    bf16x8 af[4], bf[4];
#pragma unroll
    for (int mt = 0; mt < 4; ++mt) {
      int row = mt * 16 + (l & 15);
      int cb = (kc * 4 + (l >> 4)) ^ (row & 7);
      af[mt] = *(const bf16x8*)(sEc + row * 512 + cb * 16);
    }
#pragma unroll
    for (int nt = 0; nt < 4; ++nt)
      bf[nt] = *(const bf16x8*)&sB[w * 64 + nt * 16 + (l & 15)][(l >> 4) * 8];
#pragma unroll
    for (int mt = 0; mt < 4; ++mt)
#pragma unroll
      for (int nt = 0; nt < 4; ++nt)
        accP[mt][nt] = __builtin_amdgcn_mfma_f32_16x16x32_bf16(af[mt], bf[nt], accP[mt][nt], 0, 0, 0);
    if (w == 0) {  // fused sed1
      bf16x8 bs = ((l & 15) < 4)
          ? *(const bf16x8*)&sEd1[l & 15][kc * 32 + (l >> 4) * 8] : z8;
#pragma unroll
      for (int mt = 0; mt < 4; ++mt)
        accs[mt] = __builtin_amdgcn_mfma_f32_16x16x32_bf16(af[mt], bs, accs[mt], 0, 0, 0);
    }
  }
#pragma unroll
  for (int mt = 0; mt < 4; ++mt)
#pragma unroll
    for (int nt = 0; nt < 4; ++nt)
#pragma unroll
      for (int i = 0; i < 4; ++i) {
        long row = e0 + mt * 16 + (l >> 4) * 4 + i;
        int col = w * 64 + nt * 16 + (l & 15);
        eprojL1[row * 256 + col] = f2b(accP[mt][nt][i]);
      }
  if (w == 0 && (l & 15) < 4) {
#pragma unroll
    for (int mt = 0; mt < 4; ++mt)
#pragma unroll
      for (int i = 0; i < 4; ++i) {
        long row = e0 + mt * 16 + (l >> 4) * 4 + i;
        sed1[row * 4 + (l & 15)] = accs[mt][i];
      }
  }
}

// ---------- fused node layer: out = elu(xin@W_self + sum_k alpha_k * eproj[e_k]) ----------
__global__ __launch_bounds__(256, 2) void node_out(
    const ushort_t* __restrict__ xb,     // bf16 [N][256] (xin)
    const int* __restrict__ n2e,         // [N][8]
    const ushort_t* __restrict__ eproj,  // bf16 [E][256]
    const float* __restrict__ sed,       // f32 [E][4]
    const float* __restrict__ a_s,       // f32 [4][256]
    const ushort_t* __restrict__ WtS,    // bf16 [256][256]
    float* __restrict__ outp,            // f32, row stride 512
    ushort_t* __restrict__ xout) {       // bf16 [N][256] or nullptr
  __shared__ __align__(16) char smem[33280 + 1024 + 4096 + 4096];
  ushort_t (*sX)[32]   = (ushort_t(*)[32])smem;            // [32][32]   (K-loop)
  ushort_t (*sBs)[32]  = (ushort_t(*)[32])(smem + 2048);   // [256][32]  (K-loop)
  ushort_t (*sAs)[256] = (ushort_t(*)[256])(smem + 18432); // [4][256]   (K-loop)
  float* sOutF         = (float*)smem;                      // overlay [32][260] f32 (33280B)
  int*   sIdx          = (int*)(smem + 33280);              // [256]
  float* sSe           = (float*)(smem + 34304);            // [256][4]
  float* sAln          = (float*)(smem + 38400);            // [32][4][8]
  int t = threadIdx.x, w = t >> 6, l = t & 63;
  long n0 = (long)blockIdx.x * 32;

  {  // prologue: edge ids + score gather
    int e = n2e[n0 * 8 + t];
    sIdx[t] = e;
    *(float4*)&sSe[t * 4] = *(const float4*)(sed + (long)e * 4);
  }
  if (t < 128) {  // stage a_s as bf16
    int row = t >> 5, dof = (t & 31) * 8;
    float f[8]; ld8(a_s + row * 256 + dof, f);
    *(uint4*)&sAs[row][dof] = enc8(f);
  }

  f32x4 zero = {0.f, 0.f, 0.f, 0.f};
  f32x4 acc[2][4];
#pragma unroll
  for (int mt = 0; mt < 2; ++mt)
#pragma unroll
    for (int nt = 0; nt < 4; ++nt) acc[mt][nt] = zero;
  float ssp = 0.f;
  int sn = t >> 3, shalf = (t & 1) * 16, sh = (t >> 1) & 3;

  for (int kc = 0; kc < 8; ++kc) {
    __syncthreads();
    if (w == 0) {
#pragma unroll
      for (int j = 0; j < 2; ++j) {
        int u = j * 64 + l;
        int r = u >> 2, ks = u & 3;
        async16((char*)sX + j * 1024, xb + (n0 + r) * 256 + kc * 32 + ks * 8);
      }
    }
#pragma unroll
    for (int j = 0; j < 4; ++j) {
      int u = (w * 4 + j) * 64 + l;
      int n = u >> 2, ks = u & 3;
      async16((char*)sBs + (w * 4 + j) * 1024, WtS + (long)n * 256 + kc * 32 + ks * 8);
    }
    __syncthreads();
    bf16x8 ax[2], bs[4];
#pragma unroll
    for (int mt = 0; mt < 2; ++mt)
      ax[mt] = *(const bf16x8*)&sX[mt * 16 + (l & 15)][(l >> 4) * 8];
#pragma unroll
    for (int nt = 0; nt < 4; ++nt)
      bs[nt] = *(const bf16x8*)&sBs[w * 64 + nt * 16 + (l & 15)][(l >> 4) * 8];
#pragma unroll
    for (int mt = 0; mt < 2; ++mt)
#pragma unroll
      for (int nt = 0; nt < 4; ++nt)
        acc[mt][nt] = __builtin_amdgcn_mfma_f32_16x16x32_bf16(ax[mt], bs[nt], acc[mt][nt], 0, 0, 0);
    {  // fused ss partial: thread (node sn, head sh, half) does 16 dims
      float xv[16], av[16];
      dec8(*(const uint4*)&sX[sn][shalf], xv);
      dec8(*(const uint4*)&sX[sn][shalf + 8], xv + 8);
      dec8(*(const uint4*)&sAs[sh][kc * 32 + shalf], av);
      dec8(*(const uint4*)&sAs[sh][kc * 32 + shalf + 8], av + 8);
#pragma unroll
      for (int d = 0; d < 16; ++d) ssp += xv[d] * av[d];
    }
  }
  __syncthreads();
#pragma unroll
  for (int mt = 0; mt < 2; ++mt)
#pragma unroll
    for (int nt = 0; nt < 4; ++nt)
#pragma unroll
      for (int i = 0; i < 4; ++i) {
        int row = mt * 16 + (l >> 4) * 4 + i;
        int col = w * 64 + nt * 16 + (l & 15);
        sOutF[row * 260 + col] = acc[mt][nt][i];
      }
  float ssv = ssp + __shfl_xor(ssp, 1, 64);
  if (!(t & 1)) {
    float sv[8], mx = -1e30f;
#pragma unroll
    for (int k = 0; k < 8; ++k) {
      float s = ssv + sSe[(sn * 8 + k) * 4 + sh];
      s = s > 0.f ? s : 0.2f * s;
      sv[k] = s; mx = fmaxf(mx, s);
    }
    float sum = 0.f;
#pragma unroll
    for (int k = 0; k < 8; ++k) { sv[k] = __expf(sv[k] - mx); sum += sv[k]; }
    float inv = 1.f / sum;
#pragma unroll
    for (int k = 0; k < 8; ++k) sAln[(sn * 4 + sh) * 8 + k] = sv[k] * inv;
  }
  __syncthreads();

  int nT = t >> 3, sT = t & 7, hh = sT >> 1, dof = sT * 32;
  float wts[8];
#pragma unroll
  for (int k = 0; k < 8; ++k) wts[k] = sAln[(nT * 4 + hh) * 8 + k];
  int eidx[8];
#pragma unroll
  for (int k = 0; k < 8; ++k) eidx[k] = sIdx[nT * 8 + k];
  float o[32];
#pragma unroll
  for (int j = 0; j < 8; ++j) {
    float4 sv = *(const float4*)&sOutF[nT * 260 + dof + j * 4];
    o[j * 4 + 0] = sv.x; o[j * 4 + 1] = sv.y; o[j * 4 + 2] = sv.z; o[j * 4 + 3] = sv.w;
  }
#pragma unroll
  for (int k = 0; k < 8; ++k) {
    const ushort_t* pr = eproj + (long)eidx[k] * 256 + dof;
    float v[32];
    dec8(*(const uint4*)(pr),      v);
    dec8(*(const uint4*)(pr + 8),  v + 8);
    dec8(*(const uint4*)(pr + 16), v + 16);
    dec8(*(const uint4*)(pr + 24), v + 24);
    float wk = wts[k];
#pragma unroll
    for (int d = 0; d < 32; ++d) o[d] += wk * v[d];
  }
  long row = n0 + nT;
  float res[32];
#pragma unroll
  for (int d = 0; d < 32; ++d) res[d] = ELUF(o[d]);
  float* po = outp + row * 512 + dof;
#pragma unroll
  for (int j = 0; j < 8; ++j) {
    float4 q;
    q.x = res[j * 4 + 0]; q.y = res[j * 4 + 1]; q.z = res[j * 4 + 2]; q.w = res[j * 4 + 3];
    *(float4*)(po + j * 4) = q;
  }
  if (xout) {
#pragma unroll
    for (int j = 0; j < 4; ++j)
      *(uint4*)(xout + row * 256 + dof + j * 8) = enc8(res + j * 8);
  }
}

extern "C" void kernel_launch(void* const* d_in, const int* in_sizes, int n_in,
                              void* d_out, int out_size, void* d_ws, size_t ws_size,
                              hipStream_t stream) {
  (void)in_sizes; (void)n_in; (void)out_size; (void)ws_size;
  const float* feats  = (const float*)d_in[0];
  const float* eemb   = (const float*)d_in[1];
  const int*   adj    = (const int*)d_in[2];
  const int*   n2e    = (const int*)d_in[3];
  const float* Wp0    = (const float*)d_in[4];
  const float* Wp1    = (const float*)d_in[5];
  const float* Wep    = (const float*)d_in[6];
  const float* a_e    = (const float*)d_in[7];
  const float* a_n    = (const float*)d_in[8];
  const float* W_e    = (const float*)d_in[9];
  const float* a_s    = (const float*)d_in[10];
  const float* a_edge = (const float*)d_in[11];
  const float* W_self = (const float*)d_in[12];
  const float* W_nb   = (const float*)d_in[13];
  float* out = (float*)d_out;

  // workspace carve (~360 MiB)
  char* w = (char*)d_ws;
  ushort_t* dummy_bf = (ushort_t*)w; w += (size_t)N_NODES * 256 * 2;
  ushort_t* base_bf  = (ushort_t*)w; w += (size_t)N_NODES * 256 * 2;
  ushort_t* eproj0   = (ushort_t*)w; w += (size_t)N_EDGES * 256 * 2;
  ushort_t* eprojL1  = (ushort_t*)w; w += (size_t)N_EDGES * 256 * 2;
  ushort_t* bufX     = (ushort_t*)w; w += (size_t)N_NODES * 256 * 2;  // xprojE then xl1
  float*    sed0     = (float*)w;    w += (size_t)N_EDGES * 4 * 4;
  float*    sed1     = (float*)w;    w += (size_t)N_EDGES * 4 * 4;
  float*    xan      = (float*)w;    w += (size_t)N_NODES * 4 * 4;
  ushort_t* gbuf     = (ushort_t*)w; w += 2 * 512 * 2;
  ushort_t* WtP0     = (ushort_t*)w; w += 256 * 256 * 2;
  ushort_t* WtP1     = (ushort_t*)w; w += 256 * 256 * 2;
  ushort_t* WtEp     = (ushort_t*)w; w += 2 * 256 * 64 * 2;
  ushort_t* WtE      = (ushort_t*)w; w += 16 * 16384 * 2;
  ushort_t* WtS      = (ushort_t*)w; w += 16 * 16384 * 2;
  ushort_t* WtN      = (ushort_t*)w; w += 16 * 16384 * 2;

  // weight pre-transpose to bf16 Wt[n][k] + folded score vectors
  wt_kernel<<<dim3(256, 1), 256, 0, stream>>>(Wp0, WtP0, 256, 256);
  wt_kernel<<<dim3(256, 1), 256, 0, stream>>>(Wp1, WtP1, 256, 256);
  wt_kernel<<<dim3(64, 2), 256, 0, stream>>>(Wep, WtEp, 64, 256);
  wt_kernel<<<dim3(64, 16), 256, 0, stream>>>(W_e, WtE, 256, 64);
  wt_kernel<<<dim3(64, 16), 256, 0, stream>>>(W_self, WtS, 256, 64);
  wt_kernel<<<dim3(64, 16), 256, 0, stream>>>(W_nb, WtN, 256, 64);
  g_kernel<<<2, 512, 0, stream>>>(Wep, a_e, a_edge, gbuf);

  // prep: dummy_bf = feats@Wp0, base_bf = feats@Wp1 in one pass over feats
  gemm_mfma2<<<N_NODES / 64, 256, 0, stream>>>(feats, WtP0, WtP1, dummy_bf, base_bf);

  for (int mp = 0; mp < 2; ++mp) {
    const int* adj_mp = adj + (size_t)mp * N_EDGES * 2;
    const int* n2e_mp = n2e + (size_t)mp * N_NODES * 8;
    size_t ao0 = (size_t)(mp * 2 + 0) * 1024, ao1 = (size_t)(mp * 2 + 1) * 1024;
    size_t wo0 = (size_t)(mp * 2 + 0) * 65536, wo1 = (size_t)(mp * 2 + 1) * 65536;

    ushort_t* xprojE = bufX;
    ushort_t* xl1    = bufX;  // alias: xprojE dead after edge_mega

    // 1. xprojE = base @ W_e(L0), xan = base . a_n(L0)
    gemm_eproj<<<N_NODES / 64, 256, 0, stream>>>(base_bf, WtE + wo0, a_n + ao0, xprojE, xan);
    // 2. whole edge pipeline
    edge_mega<<<N_EDGES / 64, 256, 0, stream>>>(
        eemb + (size_t)mp * N_EDGES * 64, WtEp + (size_t)mp * 16384,
        WtN + wo0, WtE + wo0, WtN + wo1,
        gbuf + (size_t)mp * 512, a_edge + ao1,
        adj_mp, xprojE, xan, eproj0, sed0, eprojL1, sed1);
    // 3. node layer 0 (xin = dummy prep)
    node_out<<<N_NODES / 32, 256, 0, stream>>>(dummy_bf, n2e_mp, eproj0, sed0,
                                               a_s + ao0, WtS + wo0,
                                               out + (size_t)mp * N_NODES * 512, xl1);
    // 4. node layer 1
    node_out<<<N_NODES / 32, 256, 0, stream>>>(xl1, n2e_mp, eprojL1, sed1,
                                               a_s + ao1, WtS + wo1,
                                               out + (size_t)mp * N_NODES * 512 + 256,
                                               (ushort_t*)nullptr);
  }
}

// Round 5
// 1419.516 us; speedup vs baseline: 1.3385x; 1.3385x over previous
//
#include <hip/hip_runtime.h>

typedef unsigned short ushort_t;
typedef unsigned int uint_t;

#define N_NODES 65536
#define N_EDGES 262144

typedef __attribute__((ext_vector_type(8))) short bf16x8;
typedef __attribute__((ext_vector_type(4))) float f32x4;

// ---------- bf16 helpers ----------
__device__ __forceinline__ ushort_t f2b(float x) {
  uint_t u = __float_as_uint(x);
  u += 0x7fffu + ((u >> 16) & 1u);  // RNE
  return (ushort_t)(u >> 16);
}
__device__ __forceinline__ void dec8(uint4 v, float* f) {
  f[0] = __uint_as_float(v.x << 16); f[1] = __uint_as_float(v.x & 0xffff0000u);
  f[2] = __uint_as_float(v.y << 16); f[3] = __uint_as_float(v.y & 0xffff0000u);
  f[4] = __uint_as_float(v.z << 16); f[5] = __uint_as_float(v.z & 0xffff0000u);
  f[6] = __uint_as_float(v.w << 16); f[7] = __uint_as_float(v.w & 0xffff0000u);
}
__device__ __forceinline__ uint4 enc8(const float* f) {
  uint4 v;
  v.x = (uint_t)f2b(f[0]) | ((uint_t)f2b(f[1]) << 16);
  v.y = (uint_t)f2b(f[2]) | ((uint_t)f2b(f[3]) << 16);
  v.z = (uint_t)f2b(f[4]) | ((uint_t)f2b(f[5]) << 16);
  v.w = (uint_t)f2b(f[6]) | ((uint_t)f2b(f[7]) << 16);
  return v;
}
__device__ __forceinline__ void ld8(const float* p, float* f) {
  float4 v0 = *(const float4*)p;
  float4 v1 = *(const float4*)(p + 4);
  f[0]=v0.x; f[1]=v0.y; f[2]=v0.z; f[3]=v0.w;
  f[4]=v1.x; f[5]=v1.y; f[6]=v1.z; f[7]=v1.w;
}

#define ELUF(v) ((v) > 0.f ? (v) : __expf(v) - 1.f)

// async global->LDS, 16B per lane; lds base must be wave-uniform (lane deposits at base+lane*16)
__device__ __forceinline__ void async16(void* lds, const void* g) {
  __builtin_amdgcn_global_load_lds(
      (const __attribute__((address_space(1))) void*)g,
      (__attribute__((address_space(3))) void*)lds, 16, 0, 0);
}

// B-fragment read from block-transposed LDS tile: block(n, ks) at byte ks*4096 + n*16.
// (After async16 staging of a weight buffer pre-permuted by wtp_kernel, LDS block u
// holds logical (n = u&255, ks = u>>8) -> fragment lanes read consecutive 16B blocks.)
#define BFRAG(sBase, n, q) (*(const bf16x8*)((const char*)(sBase) + (q) * 4096 + (long)(n) * 16))

// ---------- permuted weight transpose+cvt ----------
// Produces bf16 buffer such that the standard staging source formula
//   src_ushort[n'*K + kc*32 + ks'*8 + k8]  (n' = u>>2, ks' = u&3, u = lane-linear)
// deposits logical block (n = u&255, ks = u>>8) at LDS block u.
// Logical element: W[k][n] with k = kc*32 + ks*8 + k8.
// hm=0: src[k*256 + n]; hm=1: src[(n>>6)*K*64 + k*64 + (n&63)] (head-major [4][K][64]).
__global__ void wtp_kernel(const float* __restrict__ src, ushort_t* __restrict__ dst,
                           int K, int hm) {
  long m = blockIdx.y;
  const float* s = src + m * (long)K * 256;
  ushort_t* d = dst + m * (long)K * 256;
  int tid = blockIdx.x * 256 + threadIdx.x;
  if (tid >= K * 256) return;
  int kc = tid >> 13;
  int rem = tid & 8191;
  int u = rem >> 3, k8 = rem & 7;
  int n = u & 255, ks = u >> 8;
  int k = kc * 32 + ks * 8 + k8;
  float v;
  if (hm) v = s[(long)(n >> 6) * K * 64 + (long)k * 64 + (n & 63)];
  else    v = s[(long)k * 256 + n];
  d[(long)(u >> 2) * K + kc * 32 + (u & 3) * 8 + k8] = f2b(v);
}

// ---------- folded score vectors: gbuf[mp][v][c] = bf16( sum_d Wep[mp][c][d]... ) ----------
// v = 0..3 -> a_e(L0) head v ; v = 4..7 -> a_edge(L0) head v-4.  c in [0,64).
__global__ void g_kernel(const float* __restrict__ Wep, const float* __restrict__ a_e,
                         const float* __restrict__ a_edge, ushort_t* __restrict__ gbuf) {
  int mp = blockIdx.x;
  int t = threadIdx.x;       // 512 threads
  int v = t >> 6, c = t & 63;
  const float* vec = (v < 4 ? a_e + mp * 2048 + v * 256
                            : a_edge + mp * 2048 + (v - 4) * 256);
  const float* wrow = Wep + (long)mp * 64 * 256 + (long)c * 256;
  float s = 0.f;
#pragma unroll
  for (int d = 0; d < 256; d += 4) {
    float4 wv = *(const float4*)(wrow + d);
    float4 av = *(const float4*)(vec + d);
    s += wv.x * av.x + wv.y * av.y + wv.z * av.z + wv.w * av.w;
  }
  gbuf[mp * 512 + v * 64 + c] = f2b(s);
}

// ---------- dual MFMA GEMM: out{0,1}[rows][256] = bf16( A_f32[rows][256] @ Wt{0,1}^T ) ----------
__global__ __launch_bounds__(256, 2) void gemm_mfma2(
    const float* __restrict__ A, const ushort_t* __restrict__ Wt0,
    const ushort_t* __restrict__ Wt1, ushort_t* __restrict__ out0,
    ushort_t* __restrict__ out1) {
  __shared__ __align__(16) char smem[4096 + 16384 + 16384];
  char* sA  = smem;            // [4 ks][64 r] 16B blocks (block-transposed)
  char* sB0 = smem + 4096;     // [4 ks][256 n] blocks
  char* sB1 = smem + 20480;
  int t = threadIdx.x, w = t >> 6, l = t & 63;
  long r0 = (long)blockIdx.x * 64;
  f32x4 zero = {0.f, 0.f, 0.f, 0.f};
  f32x4 acc0[4][4], acc1[4][4];
#pragma unroll
  for (int mt = 0; mt < 4; ++mt)
#pragma unroll
    for (int nt = 0; nt < 4; ++nt) { acc0[mt][nt] = zero; acc1[mt][nt] = zero; }

  for (int kc = 0; kc < 8; ++kc) {
    __syncthreads();
    {  // stage A (f32 -> bf16), block-transposed store
      int r = t >> 2, ks8 = (t & 3) * 8;
      float f[8]; ld8(A + (r0 + r) * 256 + kc * 32 + ks8, f);
      *(uint4*)(sA + (t & 3) * 1024 + r * 16) = enc8(f);
    }
#pragma unroll
    for (int j = 0; j < 4; ++j) {
      int u = (w * 4 + j) * 64 + l;
      int n = u >> 2, ks = u & 3;
      async16(sB0 + (w * 4 + j) * 1024, Wt0 + (long)n * 256 + kc * 32 + ks * 8);
      async16(sB1 + (w * 4 + j) * 1024, Wt1 + (long)n * 256 + kc * 32 + ks * 8);
    }
    __syncthreads();
    int q = l >> 4;
    bf16x8 af[4];
#pragma unroll
    for (int mt = 0; mt < 4; ++mt)
      af[mt] = *(const bf16x8*)(sA + q * 1024 + (mt * 16 + (l & 15)) * 16);
#pragma unroll
    for (int nt = 0; nt < 4; ++nt) {
      int n = w * 64 + nt * 16 + (l & 15);
      bf16x8 b0 = BFRAG(sB0, n, q);
      bf16x8 b1 = BFRAG(sB1, n, q);
#pragma unroll
      for (int mt = 0; mt < 4; ++mt) {
        acc0[mt][nt] = __builtin_amdgcn_mfma_f32_16x16x32_bf16(af[mt], b0, acc0[mt][nt], 0, 0, 0);
        acc1[mt][nt] = __builtin_amdgcn_mfma_f32_16x16x32_bf16(af[mt], b1, acc1[mt][nt], 0, 0, 0);
      }
    }
  }
#pragma unroll
  for (int mt = 0; mt < 4; ++mt)
#pragma unroll
    for (int nt = 0; nt < 4; ++nt)
#pragma unroll
      for (int i = 0; i < 4; ++i) {
        long row = r0 + mt * 16 + (l >> 4) * 4 + i;
        int col = w * 64 + nt * 16 + (l & 15);
        out0[row * 256 + col] = f2b(acc0[mt][nt][i]);
        out1[row * 256 + col] = f2b(acc1[mt][nt][i]);
      }
}

// ---------- eproj GEMM: outb[rows][256] = bf16(A @ Wt^T), + fused scores[rows][4] ----------
__global__ __launch_bounds__(256, 2) void gemm_eproj(
    const ushort_t* __restrict__ A, const ushort_t* __restrict__ Wt,
    const float* __restrict__ a_vec,  // f32 [4][256]
    ushort_t* __restrict__ outb, float* __restrict__ sco) {
  __shared__ __align__(16) char smem[4096 + 16384 + 8448];
  ushort_t (*sA)[32]   = (ushort_t(*)[32])smem;            // [64][32] (linear, activation)
  char* sB             = smem + 4096;                      // transposed blocks
  ushort_t (*sAe)[264] = (ushort_t(*)[264])(smem + 20480); // [16][264] padded, rows 4..15 zero
  int t = threadIdx.x, w = t >> 6, l = t & 63;
  long r0 = (long)blockIdx.x * 64;

  {  // stage a_vec^T as B-layout tile (16 cols, cols>=4 zero)
    int row = t >> 4, seg = (t & 15) * 16;
    float f[16];
    if (row < 4) {
      ld8(a_vec + row * 256 + seg, f);
      ld8(a_vec + row * 256 + seg + 8, f + 8);
    } else {
#pragma unroll
      for (int i = 0; i < 16; ++i) f[i] = 0.f;
    }
    *(uint4*)&sAe[row][seg] = enc8(f);
    *(uint4*)&sAe[row][seg + 8] = enc8(f + 8);
  }

  f32x4 zero = {0.f, 0.f, 0.f, 0.f};
  f32x4 acc[4][4];
  f32x4 accs[4];
#pragma unroll
  for (int mt = 0; mt < 4; ++mt) {
    accs[mt] = zero;
#pragma unroll
    for (int nt = 0; nt < 4; ++nt) acc[mt][nt] = zero;
  }

  for (int kc = 0; kc < 8; ++kc) {
    __syncthreads();
    async16((char*)sA + w * 1024, A + (r0 + (t >> 2)) * 256 + kc * 32 + (t & 3) * 8);
#pragma unroll
    for (int j = 0; j < 4; ++j) {  // stage B
      int u = (w * 4 + j) * 64 + l;
      int n = u >> 2, ks = u & 3;
      async16(sB + (w * 4 + j) * 1024, Wt + (long)n * 256 + kc * 32 + ks * 8);
    }
    __syncthreads();
    int q = l >> 4;
    bf16x8 af[4], bf[4];
#pragma unroll
    for (int mt = 0; mt < 4; ++mt)
      af[mt] = *(const bf16x8*)&sA[mt * 16 + (l & 15)][q * 8];
#pragma unroll
    for (int nt = 0; nt < 4; ++nt)
      bf[nt] = BFRAG(sB, w * 64 + nt * 16 + (l & 15), q);
#pragma unroll
    for (int mt = 0; mt < 4; ++mt)
#pragma unroll
      for (int nt = 0; nt < 4; ++nt)
        acc[mt][nt] = __builtin_amdgcn_mfma_f32_16x16x32_bf16(af[mt], bf[nt], acc[mt][nt], 0, 0, 0);
    if (w == 0) {  // fused scores: A @ a_vec^T
      bf16x8 bs = *(const bf16x8*)&sAe[l & 15][kc * 32 + q * 8];
#pragma unroll
      for (int mt = 0; mt < 4; ++mt)
        accs[mt] = __builtin_amdgcn_mfma_f32_16x16x32_bf16(af[mt], bs, accs[mt], 0, 0, 0);
    }
  }
#pragma unroll
  for (int mt = 0; mt < 4; ++mt)
#pragma unroll
    for (int nt = 0; nt < 4; ++nt)
#pragma unroll
      for (int i = 0; i < 4; ++i) {
        long row = r0 + mt * 16 + (l >> 4) * 4 + i;
        int col = w * 64 + nt * 16 + (l & 15);
        outb[row * 256 + col] = f2b(acc[mt][nt][i]);
      }
  if (w == 0 && (l & 15) < 4) {
#pragma unroll
    for (int mt = 0; mt < 4; ++mt)
#pragma unroll
      for (int i = 0; i < 4; ++i) {
        long row = r0 + mt * 16 + (l >> 4) * 4 + i;
        sco[row * 4 + (l & 15)] = accs[mt][i];
      }
  }
}

// ---------- edge mega-kernel: whole edge pipeline on one resident 64x256 tile ----------
// Phase1: tile = eemb @ W_eprep -> LDS swizzled; fused sea/sed0 vs folded 64-dim g-vectors.
// PassA: tile @ W_nb(L0) -> eproj0.  PassB: tile @ W_e(L0) -> overwrite tile (= eprojE).
// Phase3: per-kc in-place combine elu(eprojE + a0*xprojE[n0] + a1*xprojE[n1]) @ W_nb(L1)
//         -> eprojL1 + fused sed1.
// sEc swizzle: 16B-block cb = (col>>3) ^ (row&7).  B tiles: block-transposed (BFRAG).
__global__ __launch_bounds__(256, 2) void edge_mega(
    const float* __restrict__ eemb,       // [E][64] f32 (this mp)
    const ushort_t* __restrict__ WtEp,    // permuted [256][64]
    const ushort_t* __restrict__ WtN0,    // permuted [256][256] W_nb L0
    const ushort_t* __restrict__ WtE0,    // permuted [256][256] W_e  L0
    const ushort_t* __restrict__ WtN1,    // permuted [256][256] W_nb L1
    const ushort_t* __restrict__ gbuf,    // [8][64] folded score vecs (this mp)
    const float* __restrict__ a_ed1,      // [4][256] a_edge L1
    const int* __restrict__ ena,          // [E][2]
    const ushort_t* __restrict__ xprojE,  // [N][256] base @ W_e(L0)
    const float* __restrict__ xan,        // [N][4]   base . a_n(L0)
    ushort_t* __restrict__ eproj0, float* __restrict__ sed0,
    ushort_t* __restrict__ eprojL1, float* __restrict__ sed1) {
  __shared__ __align__(16) char smem[54272];
  char* sEc            = smem;                              // [64 rows][512B] bf16 swizzled
  char* sB             = smem + 32768;                      // 16KB transposed B blocks
  ushort_t (*sSc0)[64] = (ushort_t(*)[64])(smem + 49152);   // [8][64] phase-1 score B
  char* sT             = smem + 50176;                      // phase-1 A-stage (transposed blocks)
  float* sSea          = (float*)(smem + 50176);            // [64][4]  (after phase 1)
  ushort_t (*sEd1)[256]= (ushort_t(*)[256])(smem + 51200);  // [4][256] (after phase 1)
  int t = threadIdx.x, w = t >> 6, l = t & 63;
  long e0 = (long)blockIdx.x * 64;
  bf16x8 z8 = {0, 0, 0, 0, 0, 0, 0, 0};

  // per-thread edge endpoints (phase 3); issue early
  int r3 = t >> 2, cq = t & 3;
  int n0r = ena[(e0 + r3) * 2 + 0];
  int n1r = ena[(e0 + r3) * 2 + 1];
  float4 x0s = *(const float4*)(xan + (long)n0r * 4);
  float4 x1s = *(const float4*)(xan + (long)n1r * 4);

  if (t < 64)  // stage folded score tile [8][64]
    *(uint4*)&sSc0[t >> 3][(t & 7) * 8] = *(const uint4*)(gbuf + (t >> 3) * 64 + (t & 7) * 8);

  f32x4 zero = {0.f, 0.f, 0.f, 0.f};
  f32x4 acc[4][4];
  f32x4 accs[4];
#pragma unroll
  for (int mt = 0; mt < 4; ++mt) {
    accs[mt] = zero;
#pragma unroll
    for (int nt = 0; nt < 4; ++nt) acc[mt][nt] = zero;
  }

  // ---- phase 1: tile = eemb @ WtEp^T (K=64) + fused L0 scores ----
  for (int kc = 0; kc < 2; ++kc) {
    __syncthreads();
    {  // stage A chunk (f32 -> bf16), block-transposed
      int r = t >> 2, ks8 = (t & 3) * 8;
      float f[8]; ld8(eemb + (e0 + r) * 64 + kc * 32 + ks8, f);
      *(uint4*)(sT + (t & 3) * 1024 + r * 16) = enc8(f);
    }
#pragma unroll
    for (int j = 0; j < 4; ++j) {
      int u = (w * 4 + j) * 64 + l;
      int n = u >> 2, ks = u & 3;
      async16(sB + (w * 4 + j) * 1024, WtEp + (long)n * 64 + kc * 32 + ks * 8);
    }
    __syncthreads();
    int q = l >> 4;
    bf16x8 af[4], bf[4];
#pragma unroll
    for (int mt = 0; mt < 4; ++mt)
      af[mt] = *(const bf16x8*)(sT + q * 1024 + (mt * 16 + (l & 15)) * 16);
#pragma unroll
    for (int nt = 0; nt < 4; ++nt)
      bf[nt] = BFRAG(sB, w * 64 + nt * 16 + (l & 15), q);
#pragma unroll
    for (int mt = 0; mt < 4; ++mt)
#pragma unroll
      for (int nt = 0; nt < 4; ++nt)
        acc[mt][nt] = __builtin_amdgcn_mfma_f32_16x16x32_bf16(af[mt], bf[nt], acc[mt][nt], 0, 0, 0);
    if (w == 0) {  // fused sea (cols 0-3) / sed0 (cols 4-7)
      bf16x8 bs = ((l & 15) < 8)
          ? *(const bf16x8*)&sSc0[l & 15][kc * 32 + q * 8] : z8;
#pragma unroll
      for (int mt = 0; mt < 4; ++mt)
        accs[mt] = __builtin_amdgcn_mfma_f32_16x16x32_bf16(af[mt], bs, accs[mt], 0, 0, 0);
    }
  }
  // write tile to sEc (bf16, swizzled)
#pragma unroll
  for (int mt = 0; mt < 4; ++mt)
#pragma unroll
    for (int nt = 0; nt < 4; ++nt)
#pragma unroll
      for (int i = 0; i < 4; ++i) {
        int row = mt * 16 + (l >> 4) * 4 + i;
        int col = w * 64 + nt * 16 + (l & 15);
        int cb = (col >> 3) ^ (row & 7);
        *(ushort_t*)(sEc + row * 512 + cb * 16 + (col & 7) * 2) = f2b(acc[mt][nt][i]);
      }
  __syncthreads();  // publish sEc; sT now dead

  if (w == 0) {  // score epilogue: sea -> sSea (LDS), sed0 -> global
    int c = l & 15;
    if (c < 8) {
#pragma unroll
      for (int mt = 0; mt < 4; ++mt)
#pragma unroll
        for (int i = 0; i < 4; ++i) {
          int row = mt * 16 + (l >> 4) * 4 + i;
          float v = accs[mt][i];
          if (c < 4) sSea[row * 4 + c] = v;
          else sed0[(e0 + row) * 4 + (c - 4)] = v;
        }
    }
  }
  if (t < 128) {  // stage a_edge(L1) as bf16 [4][256]
    int row = t >> 5, dof = (t & 31) * 8;
    float f[8]; ld8(a_ed1 + row * 256 + dof, f);
    *(uint4*)&sEd1[row][dof] = enc8(f);
  }

  // ---- pass A: eproj0 = tile @ W_nb(L0) ----
#pragma unroll
  for (int mt = 0; mt < 4; ++mt)
#pragma unroll
    for (int nt = 0; nt < 4; ++nt) acc[mt][nt] = zero;
  for (int kc = 0; kc < 8; ++kc) {
    __syncthreads();
#pragma unroll
    for (int j = 0; j < 4; ++j) {
      int u = (w * 4 + j) * 64 + l;
      int n = u >> 2, ks = u & 3;
      async16(sB + (w * 4 + j) * 1024, WtN0 + (long)n * 256 + kc * 32 + ks * 8);
    }
    __syncthreads();
    int q = l >> 4;
    bf16x8 af[4], bf[4];
#pragma unroll
    for (int mt = 0; mt < 4; ++mt) {
      int row = mt * 16 + (l & 15);
      int cb = (kc * 4 + q) ^ (row & 7);
      af[mt] = *(const bf16x8*)(sEc + row * 512 + cb * 16);
    }
#pragma unroll
    for (int nt = 0; nt < 4; ++nt)
      bf[nt] = BFRAG(sB, w * 64 + nt * 16 + (l & 15), q);
#pragma unroll
    for (int mt = 0; mt < 4; ++mt)
#pragma unroll
      for (int nt = 0; nt < 4; ++nt)
        acc[mt][nt] = __builtin_amdgcn_mfma_f32_16x16x32_bf16(af[mt], bf[nt], acc[mt][nt], 0, 0, 0);
  }
#pragma unroll
  for (int mt = 0; mt < 4; ++mt)
#pragma unroll
    for (int nt = 0; nt < 4; ++nt)
#pragma unroll
      for (int i = 0; i < 4; ++i) {
        long row = e0 + mt * 16 + (l >> 4) * 4 + i;
        int col = w * 64 + nt * 16 + (l & 15);
        eproj0[row * 256 + col] = f2b(acc[mt][nt][i]);
      }

  // ---- pass B: eprojE = tile @ W_e(L0) -> overwrite sEc after full K-loop ----
#pragma unroll
  for (int mt = 0; mt < 4; ++mt)
#pragma unroll
    for (int nt = 0; nt < 4; ++nt) acc[mt][nt] = zero;
  for (int kc = 0; kc < 8; ++kc) {
    __syncthreads();
#pragma unroll
    for (int j = 0; j < 4; ++j) {
      int u = (w * 4 + j) * 64 + l;
      int n = u >> 2, ks = u & 3;
      async16(sB + (w * 4 + j) * 1024, WtE0 + (long)n * 256 + kc * 32 + ks * 8);
    }
    __syncthreads();
    int q = l >> 4;
    bf16x8 af[4], bf[4];
#pragma unroll
    for (int mt = 0; mt < 4; ++mt) {
      int row = mt * 16 + (l & 15);
      int cb = (kc * 4 + q) ^ (row & 7);
      af[mt] = *(const bf16x8*)(sEc + row * 512 + cb * 16);
    }
#pragma unroll
    for (int nt = 0; nt < 4; ++nt)
      bf[nt] = BFRAG(sB, w * 64 + nt * 16 + (l & 15), q);
#pragma unroll
    for (int mt = 0; mt < 4; ++mt)
#pragma unroll
      for (int nt = 0; nt < 4; ++nt)
        acc[mt][nt] = __builtin_amdgcn_mfma_f32_16x16x32_bf16(af[mt], bf[nt], acc[mt][nt], 0, 0, 0);
  }
  __syncthreads();  // all reads of old tile complete
#pragma unroll
  for (int mt = 0; mt < 4; ++mt)
#pragma unroll
    for (int nt = 0; nt < 4; ++nt)
#pragma unroll
      for (int i = 0; i < 4; ++i) {
        int row = mt * 16 + (l >> 4) * 4 + i;
        int col = w * 64 + nt * 16 + (l & 15);
        int cb = (col >> 3) ^ (row & 7);
        *(ushort_t*)(sEc + row * 512 + cb * 16 + (col & 7) * 2) = f2b(acc[mt][nt][i]);
      }

  // per-thread 2-way softmax (row r3) from sSea + xan
  float a0h[4], a1h[4];
  {
    float xs0[4] = {x0s.x, x0s.y, x0s.z, x0s.w};
    float xs1[4] = {x1s.x, x1s.y, x1s.z, x1s.w};
#pragma unroll
    for (int h = 0; h < 4; ++h) {
      float sE = sSea[r3 * 4 + h];
      float s0 = xs0[h] + sE; s0 = s0 > 0.f ? s0 : 0.2f * s0;
      float s1 = xs1[h] + sE; s1 = s1 > 0.f ? s1 : 0.2f * s1;
      float mx = fmaxf(s0, s1);
      float g0 = __expf(s0 - mx), g1 = __expf(s1 - mx);
      float inv = 1.f / (g0 + g1);
      a0h[h] = g0 * inv; a1h[h] = g1 * inv;
    }
  }

  // ---- phase 3: in-place combine + @ W_nb(L1), fused sed1 ----
  f32x4 accP[4][4];
#pragma unroll
  for (int mt = 0; mt < 4; ++mt) {
    accs[mt] = zero;
#pragma unroll
    for (int nt = 0; nt < 4; ++nt) accP[mt][nt] = zero;
  }
  const ushort_t* p0 = xprojE + (long)n0r * 256 + cq * 8;
  const ushort_t* p1 = xprojE + (long)n1r * 256 + cq * 8;
  for (int kc = 0; kc < 8; ++kc) {
    __syncthreads();  // publishes sEc overwrite (kc=0); guards sB restage
#pragma unroll
    for (int j = 0; j < 4; ++j) {
      int u = (w * 4 + j) * 64 + l;
      int n = u >> 2, ks = u & 3;
      async16(sB + (w * 4 + j) * 1024, WtN1 + (long)n * 256 + kc * 32 + ks * 8);
    }
    {  // in-place combine of this k-chunk (head h = kc>>1); thread owns its 16B
      int h = kc >> 1;
      int cb = (kc * 4 + cq) ^ (r3 & 7);
      float ep[8], x0[8], x1[8], y[8];
      dec8(*(const uint4*)(sEc + r3 * 512 + cb * 16), ep);
      dec8(*(const uint4*)(p0 + kc * 32), x0);
      dec8(*(const uint4*)(p1 + kc * 32), x1);
#pragma unroll
      for (int d = 0; d < 8; ++d) {
        float v = ep[d] + a0h[h] * x0[d] + a1h[h] * x1[d];
        y[d] = ELUF(v);
      }
      *(uint4*)(sEc + r3 * 512 + cb * 16) = enc8(y);
    }
    __syncthreads();
    int q = l >> 4;
    bf16x8 af[4], bf[4];
#pragma unroll
    for (int mt = 0; mt < 4; ++mt) {
      int row = mt * 16 + (l & 15);
      int cb = (kc * 4 + q) ^ (row & 7);
      af[mt] = *(const bf16x8*)(sEc + row * 512 + cb * 16);
    }
#pragma unroll
    for (int nt = 0; nt < 4; ++nt)
      bf[nt] = BFRAG(sB, w * 64 + nt * 16 + (l & 15), q);
#pragma unroll
    for (int mt = 0; mt < 4; ++mt)
#pragma unroll
      for (int nt = 0; nt < 4; ++nt)
        accP[mt][nt] = __builtin_amdgcn_mfma_f32_16x16x32_bf16(af[mt], bf[nt], accP[mt][nt], 0, 0, 0);
    if (w == 0) {  // fused sed1
      bf16x8 bs = ((l & 15) < 4)
          ? *(const bf16x8*)&sEd1[l & 15][kc * 32 + q * 8] : z8;
#pragma unroll
      for (int mt = 0; mt < 4; ++mt)
        accs[mt] = __builtin_amdgcn_mfma_f32_16x16x32_bf16(af[mt], bs, accs[mt], 0, 0, 0);
    }
  }
#pragma unroll
  for (int mt = 0; mt < 4; ++mt)
#pragma unroll
    for (int nt = 0; nt < 4; ++nt)
#pragma unroll
      for (int i = 0; i < 4; ++i) {
        long row = e0 + mt * 16 + (l >> 4) * 4 + i;
        int col = w * 64 + nt * 16 + (l & 15);
        eprojL1[row * 256 + col] = f2b(accP[mt][nt][i]);
      }
  if (w == 0 && (l & 15) < 4) {
#pragma unroll
    for (int mt = 0; mt < 4; ++mt)
#pragma unroll
      for (int i = 0; i < 4; ++i) {
        long row = e0 + mt * 16 + (l >> 4) * 4 + i;
        sed1[row * 4 + (l & 15)] = accs[mt][i];
      }
  }
}

// ---------- fused node layer: out = elu(xin@W_self + sum_k alpha_k * eproj[e_k]) ----------
__global__ __launch_bounds__(256, 2) void node_out(
    const ushort_t* __restrict__ xb,     // bf16 [N][256] (xin)
    const int* __restrict__ n2e,         // [N][8]
    const ushort_t* __restrict__ eproj,  // bf16 [E][256]
    const float* __restrict__ sed,       // f32 [E][4]
    const float* __restrict__ a_s,       // f32 [4][256]
    const ushort_t* __restrict__ WtS,    // permuted bf16 [256][256]
    float* __restrict__ outp,            // f32, row stride 512
    ushort_t* __restrict__ xout) {       // bf16 [N][256] or nullptr
  __shared__ __align__(16) char smem[33280 + 1024 + 4096 + 4096];
  ushort_t (*sX)[32]   = (ushort_t(*)[32])smem;            // [32][32]   (K-loop, linear)
  char* sBs            = smem + 2048;                      // transposed B blocks (K-loop)
  ushort_t (*sAs)[256] = (ushort_t(*)[256])(smem + 18432); // [4][256]   (K-loop)
  float* sOutF         = (float*)smem;                      // overlay [32][260] f32 (33280B)
  int*   sIdx          = (int*)(smem + 33280);              // [256]
  float* sSe           = (float*)(smem + 34304);            // [256][4]
  float* sAln          = (float*)(smem + 38400);            // [32][4][8]
  int t = threadIdx.x, w = t >> 6, l = t & 63;
  long n0 = (long)blockIdx.x * 32;

  {  // prologue: edge ids + score gather
    int e = n2e[n0 * 8 + t];
    sIdx[t] = e;
    *(float4*)&sSe[t * 4] = *(const float4*)(sed + (long)e * 4);
  }
  if (t < 128) {  // stage a_s as bf16
    int row = t >> 5, dof = (t & 31) * 8;
    float f[8]; ld8(a_s + row * 256 + dof, f);
    *(uint4*)&sAs[row][dof] = enc8(f);
  }

  f32x4 zero = {0.f, 0.f, 0.f, 0.f};
  f32x4 acc[2][4];
#pragma unroll
  for (int mt = 0; mt < 2; ++mt)
#pragma unroll
    for (int nt = 0; nt < 4; ++nt) acc[mt][nt] = zero;
  float ssp = 0.f;
  int sn = t >> 3, shalf = (t & 1) * 16, sh = (t >> 1) & 3;

  for (int kc = 0; kc < 8; ++kc) {
    __syncthreads();
    if (w == 0) {
#pragma unroll
      for (int j = 0; j < 2; ++j) {
        int u = j * 64 + l;
        int r = u >> 2, ks = u & 3;
        async16((char*)sX + j * 1024, xb + (n0 + r) * 256 + kc * 32 + ks * 8);
      }
    }
#pragma unroll
    for (int j = 0; j < 4; ++j) {
      int u = (w * 4 + j) * 64 + l;
      int n = u >> 2, ks = u & 3;
      async16(sBs + (w * 4 + j) * 1024, WtS + (long)n * 256 + kc * 32 + ks * 8);
    }
    __syncthreads();
    int q = l >> 4;
    bf16x8 ax[2], bs[4];
#pragma unroll
    for (int mt = 0; mt < 2; ++mt)
      ax[mt] = *(const bf16x8*)&sX[mt * 16 + (l & 15)][q * 8];
#pragma unroll
    for (int nt = 0; nt < 4; ++nt)
      bs[nt] = BFRAG(sBs, w * 64 + nt * 16 + (l & 15), q);
#pragma unroll
    for (int mt = 0; mt < 2; ++mt)
#pragma unroll
      for (int nt = 0; nt < 4; ++nt)
        acc[mt][nt] = __builtin_amdgcn_mfma_f32_16x16x32_bf16(ax[mt], bs[nt], acc[mt][nt], 0, 0, 0);
    {  // fused ss partial: thread (node sn, head sh, half) does 16 dims
      float xv[16], av[16];
      dec8(*(const uint4*)&sX[sn][shalf], xv);
      dec8(*(const uint4*)&sX[sn][shalf + 8], xv + 8);
      dec8(*(const uint4*)&sAs[sh][kc * 32 + shalf], av);
      dec8(*(const uint4*)&sAs[sh][kc * 32 + shalf + 8], av + 8);
#pragma unroll
      for (int d = 0; d < 16; ++d) ssp += xv[d] * av[d];
    }
  }
  __syncthreads();
#pragma unroll
  for (int mt = 0; mt < 2; ++mt)
#pragma unroll
    for (int nt = 0; nt < 4; ++nt)
#pragma unroll
      for (int i = 0; i < 4; ++i) {
        int row = mt * 16 + (l >> 4) * 4 + i;
        int col = w * 64 + nt * 16 + (l & 15);
        sOutF[row * 260 + col] = acc[mt][nt][i];
      }
  float ssv = ssp + __shfl_xor(ssp, 1, 64);
  if (!(t & 1)) {
    float sv[8], mx = -1e30f;
#pragma unroll
    for (int k = 0; k < 8; ++k) {
      float s = ssv + sSe[(sn * 8 + k) * 4 + sh];
      s = s > 0.f ? s : 0.2f * s;
      sv[k] = s; mx = fmaxf(mx, s);
    }
    float sum = 0.f;
#pragma unroll
    for (int k = 0; k < 8; ++k) { sv[k] = __expf(sv[k] - mx); sum += sv[k]; }
    float inv = 1.f / sum;
#pragma unroll
    for (int k = 0; k < 8; ++k) sAln[(sn * 4 + sh) * 8 + k] = sv[k] * inv;
  }
  __syncthreads();

  int nT = t >> 3, sT = t & 7, hh = sT >> 1, dof = sT * 32;
  float wts[8];
#pragma unroll
  for (int k = 0; k < 8; ++k) wts[k] = sAln[(nT * 4 + hh) * 8 + k];
  int eidx[8];
#pragma unroll
  for (int k = 0; k < 8; ++k) eidx[k] = sIdx[nT * 8 + k];
  float o[32];
#pragma unroll
  for (int j = 0; j < 8; ++j) {
    float4 sv = *(const float4*)&sOutF[nT * 260 + dof + j * 4];
    o[j * 4 + 0] = sv.x; o[j * 4 + 1] = sv.y; o[j * 4 + 2] = sv.z; o[j * 4 + 3] = sv.w;
  }
#pragma unroll
  for (int k = 0; k < 8; ++k) {
    const ushort_t* pr = eproj + (long)eidx[k] * 256 + dof;
    float v[32];
    dec8(*(const uint4*)(pr),      v);
    dec8(*(const uint4*)(pr + 8),  v + 8);
    dec8(*(const uint4*)(pr + 16), v + 16);
    dec8(*(const uint4*)(pr + 24), v + 24);
    float wk = wts[k];
#pragma unroll
    for (int d = 0; d < 32; ++d) o[d] += wk * v[d];
  }
  long row = n0 + nT;
  float res[32];
#pragma unroll
  for (int d = 0; d < 32; ++d) res[d] = ELUF(o[d]);
  float* po = outp + row * 512 + dof;
#pragma unroll
  for (int j = 0; j < 8; ++j) {
    float4 q;
    q.x = res[j * 4 + 0]; q.y = res[j * 4 + 1]; q.z = res[j * 4 + 2]; q.w = res[j * 4 + 3];
    *(float4*)(po + j * 4) = q;
  }
  if (xout) {
#pragma unroll
    for (int j = 0; j < 4; ++j)
      *(uint4*)(xout + row * 256 + dof + j * 8) = enc8(res + j * 8);
  }
}

extern "C" void kernel_launch(void* const* d_in, const int* in_sizes, int n_in,
                              void* d_out, int out_size, void* d_ws, size_t ws_size,
                              hipStream_t stream) {
  (void)in_sizes; (void)n_in; (void)out_size; (void)ws_size;
  const float* feats  = (const float*)d_in[0];
  const float* eemb   = (const float*)d_in[1];
  const int*   adj    = (const int*)d_in[2];
  const int*   n2e    = (const int*)d_in[3];
  const float* Wp0    = (const float*)d_in[4];
  const float* Wp1    = (const float*)d_in[5];
  const float* Wep    = (const float*)d_in[6];
  const float* a_e    = (const float*)d_in[7];
  const float* a_n    = (const float*)d_in[8];
  const float* W_e    = (const float*)d_in[9];
  const float* a_s    = (const float*)d_in[10];
  const float* a_edge = (const float*)d_in[11];
  const float* W_self = (const float*)d_in[12];
  const float* W_nb   = (const float*)d_in[13];
  float* out = (float*)d_out;

  // workspace carve (~360 MiB)
  char* w = (char*)d_ws;
  ushort_t* dummy_bf = (ushort_t*)w; w += (size_t)N_NODES * 256 * 2;
  ushort_t* base_bf  = (ushort_t*)w; w += (size_t)N_NODES * 256 * 2;
  ushort_t* eproj0   = (ushort_t*)w; w += (size_t)N_EDGES * 256 * 2;
  ushort_t* eprojL1  = (ushort_t*)w; w += (size_t)N_EDGES * 256 * 2;
  ushort_t* bufX     = (ushort_t*)w; w += (size_t)N_NODES * 256 * 2;  // xprojE then xl1
  float*    sed0     = (float*)w;    w += (size_t)N_EDGES * 4 * 4;
  float*    sed1     = (float*)w;    w += (size_t)N_EDGES * 4 * 4;
  float*    xan      = (float*)w;    w += (size_t)N_NODES * 4 * 4;
  ushort_t* gbuf     = (ushort_t*)w; w += 2 * 512 * 2;
  ushort_t* WtP0     = (ushort_t*)w; w += 256 * 256 * 2;
  ushort_t* WtP1     = (ushort_t*)w; w += 256 * 256 * 2;
  ushort_t* WtEp     = (ushort_t*)w; w += 2 * 256 * 64 * 2;
  ushort_t* WtE      = (ushort_t*)w; w += 16 * 16384 * 2;
  ushort_t* WtS      = (ushort_t*)w; w += 16 * 16384 * 2;
  ushort_t* WtN      = (ushort_t*)w; w += 16 * 16384 * 2;

  // weight pre-transpose to permuted bf16 layout + folded score vectors
  wtp_kernel<<<dim3(256, 1), 256, 0, stream>>>(Wp0, WtP0, 256, 0);
  wtp_kernel<<<dim3(256, 1), 256, 0, stream>>>(Wp1, WtP1, 256, 0);
  wtp_kernel<<<dim3(64, 2), 256, 0, stream>>>(Wep, WtEp, 64, 0);
  wtp_kernel<<<dim3(256, 4), 256, 0, stream>>>(W_e, WtE, 256, 1);
  wtp_kernel<<<dim3(256, 4), 256, 0, stream>>>(W_self, WtS, 256, 1);
  wtp_kernel<<<dim3(256, 4), 256, 0, stream>>>(W_nb, WtN, 256, 1);
  g_kernel<<<2, 512, 0, stream>>>(Wep, a_e, a_edge, gbuf);

  // prep: dummy_bf = feats@Wp0, base_bf = feats@Wp1 in one pass over feats
  gemm_mfma2<<<N_NODES / 64, 256, 0, stream>>>(feats, WtP0, WtP1, dummy_bf, base_bf);

  for (int mp = 0; mp < 2; ++mp) {
    const int* adj_mp = adj + (size_t)mp * N_EDGES * 2;
    const int* n2e_mp = n2e + (size_t)mp * N_NODES * 8;
    size_t ao0 = (size_t)(mp * 2 + 0) * 1024, ao1 = (size_t)(mp * 2 + 1) * 1024;
    size_t wo0 = (size_t)(mp * 2 + 0) * 65536, wo1 = (size_t)(mp * 2 + 1) * 65536;

    ushort_t* xprojE = bufX;
    ushort_t* xl1    = bufX;  // alias: xprojE dead after edge_mega

    // 1. xprojE = base @ W_e(L0), xan = base . a_n(L0)
    gemm_eproj<<<N_NODES / 64, 256, 0, stream>>>(base_bf, WtE + wo0, a_n + ao0, xprojE, xan);
    // 2. whole edge pipeline
    edge_mega<<<N_EDGES / 64, 256, 0, stream>>>(
        eemb + (size_t)mp * N_EDGES * 64, WtEp + (size_t)mp * 16384,
        WtN + wo0, WtE + wo0, WtN + wo1,
        gbuf + (size_t)mp * 512, a_edge + ao1,
        adj_mp, xprojE, xan, eproj0, sed0, eprojL1, sed1);
    // 3. node layer 0 (xin = dummy prep)
    node_out<<<N_NODES / 32, 256, 0, stream>>>(dummy_bf, n2e_mp, eproj0, sed0,
                                               a_s + ao0, WtS + wo0,
                                               out + (size_t)mp * N_NODES * 512, xl1);
    // 4. node layer 1
    node_out<<<N_NODES / 32, 256, 0, stream>>>(xl1, n2e_mp, eprojL1, sed1,
                                               a_s + ao1, WtS + wo1,
                                               out + (size_t)mp * N_NODES * 512 + 256,
                                               (ushort_t*)nullptr);
  }
}